// Round 10
// baseline (303.071 us; speedup 1.0000x reference)
//
#include <hip/hip_runtime.h>

#define NN 100000
#define NE 1000000
#define BSH 9        // sort bucket: 512 cols
#define BCOLS 512
#define NBUCK 196    // ceil(NN/512)
#define SBLK 128     // hist/scatter edge-partition blocks (runs ~40 edges / 320 B)
#define STHR 512
#define YSTRIDE 32   // y row: 21 raw floats + pad -> 128 B aligned
#define AGB 1024     // bagg block threads
#define CAP_H 4096   // idx16 capacity per half-bucket (mean 2560, +30 sigma)

// ---------------------------------------------------------------------------
// K_f: fuse linear chain into Mt[128][24]:
//   Mt[k][0..20] = fused GCN->layer1 column k ([Wu@W1_top; Wm@W1_bot])
//   Mt[k][21]    = b1'[k],  Mt[k][22] = W2[k],  Mt[k][23] = pad
// ---------------------------------------------------------------------------
__global__ __launch_bounds__(128) void fuse_kernel(const float* __restrict__ Wu,
                                                   const float* __restrict__ bu,
                                                   const float* __restrict__ Wm,
                                                   const float* __restrict__ bm,
                                                   const float* __restrict__ W1,
                                                   const float* __restrict__ b1,
                                                   const float* __restrict__ W2,
                                                   float* __restrict__ Mt) {
    const int j = threadIdx.x;
    float w1c[128];
#pragma unroll
    for (int k = 0; k < 128; k++) w1c[k] = W1[k * 128 + j];

    float* row = Mt + j * 24;
#pragma unroll
    for (int m = 0; m < 3; m++) {
        float acc = 0.f;
#pragma unroll
        for (int k = 0; k < 64; k++) acc = fmaf(Wu[m * 64 + k], w1c[k], acc);
        row[m] = acc;
    }
#pragma unroll
    for (int m = 0; m < 18; m++) {
        float acc = 0.f;
#pragma unroll
        for (int k = 0; k < 64; k++) acc = fmaf(Wm[m * 64 + k], w1c[64 + k], acc);
        row[3 + m] = acc;
    }
    float bp = b1[j];
#pragma unroll
    for (int k = 0; k < 64; k++) {
        bp = fmaf(bu[k], w1c[k], bp);
        bp = fmaf(bm[k], w1c[64 + k], bp);
    }
    row[21] = bp;
    row[22] = W2[j];
    row[23] = 0.f;
}

// ---------------------------------------------------------------------------
// K_y: pack RAW features y[c][0..20] = [ux_c, mx_c] (no dinv — prescaling
// moved to the edge weight). 128-B aligned rows. No dependencies.
// ---------------------------------------------------------------------------
__global__ __launch_bounds__(256) void ypack_kernel(const float* __restrict__ ux,
                                                    const float* __restrict__ mx,
                                                    float* __restrict__ y) {
    const int c = blockIdx.x * 256 + threadIdx.x;
    if (c >= NN) return;
    float yr[21];
    const float* uc = ux + (size_t)c * 3;
    const float* mc = mx + (size_t)c * 18;
    yr[0] = uc[0]; yr[1] = uc[1]; yr[2] = uc[2];
#pragma unroll
    for (int k = 0; k < 18; k++) yr[3 + k] = mc[k];
    float* yo = y + (size_t)c * YSTRIDE;
#pragma unroll
    for (int q = 0; q < 5; q++)
        ((float4*)yo)[q] = make_float4(yr[4 * q], yr[4 * q + 1],
                                       yr[4 * q + 2], yr[4 * q + 3]);
    yo[20] = yr[20];
}

// ---------------------------------------------------------------------------
// K_a: per-(block,bucket) LDS histogram + global fp32 degree atomics.
// deg (= dinv array) must be zeroed before this kernel.
// ---------------------------------------------------------------------------
__global__ __launch_bounds__(STHR) void histdeg_kernel(const int* __restrict__ col,
                                                       const float* __restrict__ ew,
                                                       int* __restrict__ H,
                                                       float* __restrict__ deg) {
    __shared__ int h[NBUCK];
    for (int i = threadIdx.x; i < NBUCK; i += STHR) h[i] = 0;
    __syncthreads();
    for (int e = blockIdx.x * STHR + threadIdx.x; e < NE; e += SBLK * STHR) {
        const int c = col[e];
        atomicAdd(&h[c >> BSH], 1);
        atomicAdd(&deg[c], ew[e]);
    }
    __syncthreads();
    for (int b = threadIdx.x; b < NBUCK; b += STHR)
        H[b * SBLK + blockIdx.x] = h[b];
}

// ---------------------------------------------------------------------------
// K_v: dinv[c] = rsqrt(deg[c] + 1)  (in place)
// ---------------------------------------------------------------------------
__global__ __launch_bounds__(256) void dinv_kernel(float* __restrict__ deg) {
    const int c = blockIdx.x * 256 + threadIdx.x;
    if (c < NN) deg[c] = rsqrtf(deg[c] + 1.0f);
}

// ---------------------------------------------------------------------------
// K_b: exclusive scan of H (NBUCK*SBLK = 25088 ints) in one block.
// ---------------------------------------------------------------------------
__global__ __launch_bounds__(1024) void bscan_kernel(int* __restrict__ H) {
    const int TOT = NBUCK * SBLK;          // 25088
    const int PER = 25;                    // 1024*25 >= TOT
    const int t = threadIdx.x;
    const int base = t * PER;
    int v[PER];
    int sum = 0;
#pragma unroll
    for (int i = 0; i < PER; i++) {
        int idx = base + i;
        v[i] = (idx < TOT) ? H[idx] : 0;
        sum += v[i];
    }
    __shared__ int s[1024];
    s[t] = sum;
    __syncthreads();
    for (int off = 1; off < 1024; off <<= 1) {
        int x = (t >= off) ? s[t - off] : 0;
        __syncthreads();
        s[t] += x;
        __syncthreads();
    }
    int run = s[t] - sum;
#pragma unroll
    for (int i = 0; i < PER; i++) {
        int idx = base + i;
        if (idx < TOT) H[idx] = run;
        run += v[i];
    }
}

// ---------------------------------------------------------------------------
// K_c: deterministic scatter into per-(bucket,block) runs, with the edge
// weight PRE-SCALED: w' = dinv[row]*w. Payload x = (col&511)|(row<<9).
// ---------------------------------------------------------------------------
__global__ __launch_bounds__(STHR) void bscatter_kernel(const int* __restrict__ ei,
                                                        const float* __restrict__ ew,
                                                        const float* __restrict__ dinv,
                                                        const int* __restrict__ H,
                                                        int2* __restrict__ mid) {
    __shared__ int rbase[NBUCK];
    __shared__ int rcnt[NBUCK];
    for (int i = threadIdx.x; i < NBUCK; i += STHR) {
        rbase[i] = H[i * SBLK + blockIdx.x];
        rcnt[i] = 0;
    }
    __syncthreads();
    for (int e = blockIdx.x * STHR + threadIdx.x; e < NE; e += SBLK * STHR) {
        const int c = ei[NE + e];
        const int r = ei[e];
        const float wp = dinv[r] * ew[e];
        const int b = c >> BSH;
        const int pos = rbase[b] + atomicAdd(&rcnt[b], 1);
        mid[pos] = make_int2((c & (BCOLS - 1)) | (r << BSH), __float_as_int(wp));
    }
}

// ---------------------------------------------------------------------------
// K_e: half-bucket agg + MLP. 2 blocks per bucket x 1024 thr. Each block
// filters+sorts ONLY its 256 cols into an LDS idx16 permutation (no global
// writes), then each wave walks its 16 cols as ONE merged edge stream
// (3 edge-groups x 21 features, 2-deep edge / 1-deep y pipeline), flushing
// register accumulators to sbuf at col boundaries. Self-loop + dc scaling,
// then the MLP (wave-uniform scalar Mt loads, 4-way k-split).
// ---------------------------------------------------------------------------
__global__ __launch_bounds__(AGB) void bagg_mlp_kernel(const int2* __restrict__ mid,
                                                       const int* __restrict__ H,
                                                       const float* __restrict__ dinv,
                                                       const float* __restrict__ y,
                                                       const float* __restrict__ Mt,
                                                       const float* __restrict__ b2,
                                                       float* __restrict__ out) {
    __shared__ unsigned short idx16[CAP_H];   // 8 KB
    __shared__ int cbase[257];
    __shared__ int ccur[256];
    __shared__ float sbuf[256 * 21];          // 21.5 KB
    __shared__ float obuf[3 * 256];           // 3 KB
    __shared__ int ovf;

    const int b = blockIdx.x >> 1;
    const int half = blockIdx.x & 1;
    const int t = threadIdx.x;
    const int start = H[b * SBLK];
    const int end = (b + 1 < NBUCK) ? H[(b + 1) * SBLK] : NE;
    const int seg = end - start;

    for (int i = t; i < 256 * 21; i += AGB) sbuf[i] = 0.f;
    if (t < 256) ccur[t] = 0;
    if (t == 0) ovf = 0;
    __syncthreads();

    // phase 1: count own-half cols
    for (int i = t; i < seg; i += AGB) {
        const int cl = mid[start + i].x & (BCOLS - 1);
        if ((cl >> 8) == half) atomicAdd(&ccur[cl & 255], 1);
    }
    __syncthreads();

    // phase 2: exclusive scan of 256 counts
    int myc = 0;
    if (t < 256) { myc = ccur[t]; cbase[t] = myc; }
    __syncthreads();
    for (int off = 1; off < 256; off <<= 1) {
        int x = 0;
        if (t < 256 && t >= off) x = cbase[t - off];
        __syncthreads();
        if (t < 256) cbase[t] += x;
        __syncthreads();
    }
    if (t < 256) {
        const int incl = cbase[t];
        cbase[t] = incl - myc;
        ccur[t] = incl - myc;
        if (t == 255) {
            cbase[256] = incl;
            if (incl > CAP_H) ovf = 1;
        }
    }
    __syncthreads();

    if (!ovf) {
        // phase 3: permutation for own half
        for (int i = t; i < seg; i += AGB) {
            const int cl = mid[start + i].x & (BCOLS - 1);
            if ((cl >> 8) == half) {
                const int pos = atomicAdd(&ccur[cl & 255], 1);
                idx16[pos] = (unsigned short)i;
            }
        }
        __syncthreads();

        // phase 4: merged-stream walk; wave w owns local cols [w*16, w*16+16)
        const int wave = t >> 6;
        const int lane = t & 63;
        const int g = lane / 21;              // 0..2 active; lane 63 idle
        const int m = lane - g * 21;
        const int estart = cbase[wave * 16];
        const int eend = cbase[wave * 16 + 16];

        if (g < 3) {
            float acc = 0.f;
            int curcl = -1;
            int i0 = estart + g;
            bool v0 = i0 < eend;
            int2 e0 = v0 ? mid[start + idx16[i0]] : make_int2(0, 0);
            int i1 = i0 + 3;
            bool v1 = i1 < eend;
            int2 e1 = v1 ? mid[start + idx16[i1]] : make_int2(0, 0);
            float y0 = v0 ? y[((size_t)(((unsigned)e0.x) >> BSH) << 5) + m] : 0.f;
            int i2 = i1 + 3;
            while (v0) {
                const bool v2 = i2 < eend;
                const int2 e2 = v2 ? mid[start + idx16[i2]] : make_int2(0, 0);
                const float y1 = v1 ? y[((size_t)(((unsigned)e1.x) >> BSH) << 5) + m] : 0.f;
                const int cl = e0.x & 255;
                if (cl != curcl) {
                    if (curcl >= 0) atomicAdd(&sbuf[curcl * 21 + m], acc);
                    curcl = cl;
                    acc = 0.f;
                }
                acc = fmaf(__int_as_float(e0.y), y0, acc);
                e0 = e1; e1 = e2; y0 = y1;
                v0 = v1; v1 = v2;
                i2 += 3;
            }
            if (curcl >= 0) atomicAdd(&sbuf[curcl * 21 + m], acc);
        }
        __syncthreads();
    } else {
        // fallback (half-seg > CAP_H; statistically never): direct scan,
        // single writer per col.
        if (t < 256) {
            const int target = (half << 8) | t;
            for (int i = 0; i < seg; i++) {
                const int2 p = mid[start + i];
                if ((p.x & (BCOLS - 1)) == target) {
                    const float w = __int_as_float(p.y);
                    const float* yr = y + ((size_t)(((unsigned)p.x) >> BSH) << 5);
                    for (int mm = 0; mm < 21; mm++)
                        sbuf[t * 21 + mm] += w * yr[mm];
                }
            }
        }
        __syncthreads();
    }

    // phase 4b: self-loop + dc scaling: s = dc*(agg + dc*y_c)
    for (int i = t; i < 256 * 21; i += AGB) {
        const int lc = i / 21;
        const int m = i - lc * 21;
        const int c = b * BCOLS + (half << 8) + lc;
        if (c < NN) {
            const float dc = dinv[c];
            sbuf[i] = dc * fmaf(dc, y[((size_t)c << 5) + m], sbuf[i]);
        }
    }
    __syncthreads();

    // phase 5: MLP. t = lc + 256*kq; kq wave-uniform -> scalar Mt loads.
    const int lc = t & 255;
    const int kq = t >> 8;
    const int c = b * BCOLS + (half << 8) + lc;
    float s21[21];
#pragma unroll
    for (int mm = 0; mm < 21; mm++) s21[mm] = sbuf[lc * 21 + mm];
    float o = 0.f;
    const float* mb = Mt + kq * 32 * 24;
#pragma unroll 4
    for (int k = 0; k < 32; k++) {
        const float* r = mb + k * 24;
        float h = r[21];
#pragma unroll
        for (int mm = 0; mm < 21; mm++) h = fmaf(s21[mm], r[mm], h);
        o = fmaf(fmaxf(h, 0.f), r[22], o);
    }
    if (kq > 0) obuf[(kq - 1) * 256 + lc] = o;
    __syncthreads();
    if (kq == 0 && c < NN)
        out[c] = o + obuf[lc] + obuf[256 + lc] + obuf[512 + lc] + b2[0];
}

// ===========================================================================
extern "C" void kernel_launch(void* const* d_in, const int* in_sizes, int n_in,
                              void* d_out, int out_size, void* d_ws, size_t ws_size,
                              hipStream_t stream) {
    const float* ux = (const float*)d_in[0];   // user_x  [N,3]
    const float* mx = (const float*)d_in[1];   // movie_x [N,18]
    const int* ei = (const int*)d_in[2];       // edge_index [2,E]
    const float* ew = (const float*)d_in[3];   // edge_attr [E]
    const float* Wu = (const float*)d_in[4];   // [3,64]
    const float* bu = (const float*)d_in[5];   // [64]
    const float* Wm = (const float*)d_in[6];   // [18,64]
    const float* bm = (const float*)d_in[7];   // [64]
    const float* W1 = (const float*)d_in[8];   // [128,128]
    const float* b1 = (const float*)d_in[9];   // [128]
    const float* W2 = (const float*)d_in[10];  // [128,1]
    const float* b2 = (const float*)d_in[11];  // [1]
    float* out = (float*)d_out;

    char* ws = (char*)d_ws;
    float* dinv = (float*)ws;                           // 400,384 B (deg->dinv)
    int*   H    = (int*)(ws + 400384);                  // 25088*4 = 100,352 B
    float* Mt   = (float*)(ws + 500736);                // 12,288 B
    float* y    = (float*)(ws + 513024);                // 128-B aligned; 12.8 MB
    int2*  mid  = (int2*)(ws + 513024 + (size_t)NN * YSTRIDE * 4);   // 8 MB
    // total ~21.3 MB

    hipMemsetAsync(dinv, 0, NN * sizeof(float), stream);
    fuse_kernel<<<1, 128, 0, stream>>>(Wu, bu, Wm, bm, W1, b1, W2, Mt);
    ypack_kernel<<<(NN + 255) / 256, 256, 0, stream>>>(ux, mx, y);
    histdeg_kernel<<<SBLK, STHR, 0, stream>>>(ei + NE, ew, H, dinv);
    dinv_kernel<<<(NN + 255) / 256, 256, 0, stream>>>(dinv);
    bscan_kernel<<<1, 1024, 0, stream>>>(H);
    bscatter_kernel<<<SBLK, STHR, 0, stream>>>(ei, ew, dinv, H, mid);
    bagg_mlp_kernel<<<NBUCK * 2, AGB, 0, stream>>>(mid, H, dinv, y, Mt, b2, out);
}

// Round 11
// 271.986 us; speedup vs baseline: 1.1143x; 1.1143x over previous
//
#include <hip/hip_runtime.h>

#define NN 100000
#define NE 1000000
#define BSH 9          // bucket = 512 cols
#define BCOLS 512
#define NBUCK 196      // ceil(NN/512)
#define NNP (NBUCK * BCOLS)   // 100352 padded cols
#define PBLK 256       // plumbing grid blocks
#define PTHR 256       // plumbing block threads
#define CAP_E 6144     // LDS payload capacity (mean 5102, sd ~71 -> +14 sigma)
#define YSTRIDE 32     // y row: 21 floats + pad = 128 B
#define AGB 1024

// ---------------------------------------------------------------------------
// K_f: fuse linear chain into Mt[128][24]:
//   Mt[k][0..20] = fused GCN->layer1 column k ([Wu@W1_top; Wm@W1_bot])
//   Mt[k][21]    = b1'[k],  Mt[k][22] = W2[k],  Mt[k][23] = pad
// ---------------------------------------------------------------------------
__global__ __launch_bounds__(128) void fuse_kernel(const float* __restrict__ Wu,
                                                   const float* __restrict__ bu,
                                                   const float* __restrict__ Wm,
                                                   const float* __restrict__ bm,
                                                   const float* __restrict__ W1,
                                                   const float* __restrict__ b1,
                                                   const float* __restrict__ W2,
                                                   float* __restrict__ Mt) {
    const int j = threadIdx.x;
    float w1c[128];
#pragma unroll
    for (int k = 0; k < 128; k++) w1c[k] = W1[k * 128 + j];

    float* row = Mt + j * 24;
#pragma unroll
    for (int m = 0; m < 3; m++) {
        float acc = 0.f;
#pragma unroll
        for (int k = 0; k < 64; k++) acc = fmaf(Wu[m * 64 + k], w1c[k], acc);
        row[m] = acc;
    }
#pragma unroll
    for (int m = 0; m < 18; m++) {
        float acc = 0.f;
#pragma unroll
        for (int k = 0; k < 64; k++) acc = fmaf(Wm[m * 64 + k], w1c[64 + k], acc);
        row[3 + m] = acc;
    }
    float bp = b1[j];
#pragma unroll
    for (int k = 0; k < 64; k++) {
        bp = fmaf(bu[k], w1c[k], bp);
        bp = fmaf(bm[k], w1c[64 + k], bp);
    }
    row[21] = bp;
    row[22] = W2[j];
    row[23] = 0.f;
}

// ---------------------------------------------------------------------------
// K_a: vectorized per-(block,bucket) histogram + global fp32 degree atomics
// (fire-and-forget into 400 KB L2-resident deg). deg pre-zeroed.
// ---------------------------------------------------------------------------
__global__ __launch_bounds__(PTHR) void histdeg_kernel(const int* __restrict__ col,
                                                       const float* __restrict__ ew,
                                                       int* __restrict__ H,
                                                       float* __restrict__ deg) {
    __shared__ int h[NBUCK];
    for (int i = threadIdx.x; i < NBUCK; i += PTHR) h[i] = 0;
    __syncthreads();
    const int tid = blockIdx.x * PTHR + threadIdx.x;
    const int4* col4 = (const int4*)col;
    const float4* ew4 = (const float4*)ew;
    for (int i = tid; i < NE / 4; i += PBLK * PTHR) {
        const int4 c = col4[i];
        const float4 w = ew4[i];
        atomicAdd(&h[c.x >> BSH], 1);
        atomicAdd(&h[c.y >> BSH], 1);
        atomicAdd(&h[c.z >> BSH], 1);
        atomicAdd(&h[c.w >> BSH], 1);
        atomicAdd(&deg[c.x], w.x);
        atomicAdd(&deg[c.y], w.y);
        atomicAdd(&deg[c.z], w.z);
        atomicAdd(&deg[c.w], w.w);
    }
    __syncthreads();
    for (int b = threadIdx.x; b < NBUCK; b += PTHR)
        H[b * PBLK + blockIdx.x] = h[b];
}

// ---------------------------------------------------------------------------
// K_v: dinv = rsqrt(deg + 1), over padded range (pad deg = 0 -> dinv = 1).
// ---------------------------------------------------------------------------
__global__ __launch_bounds__(256) void dinv_kernel(float* __restrict__ deg) {
    const int c = blockIdx.x * 256 + threadIdx.x;
    if (c < NNP) deg[c] = rsqrtf(deg[c] + 1.0f);
}

// ---------------------------------------------------------------------------
// K_y: pack y[c][0..20] = dinv[c]*[ux_c, mx_c]; zeros for pad rows.
// ---------------------------------------------------------------------------
__global__ __launch_bounds__(256) void ypack_kernel(const float* __restrict__ ux,
                                                    const float* __restrict__ mx,
                                                    const float* __restrict__ dinv,
                                                    float* __restrict__ y) {
    const int c = blockIdx.x * 256 + threadIdx.x;
    if (c >= NNP) return;
    float yr[21];
    if (c < NN) {
        const float dc = dinv[c];
        const float* uc = ux + (size_t)c * 3;
        const float* mc = mx + (size_t)c * 18;
        yr[0] = dc * uc[0]; yr[1] = dc * uc[1]; yr[2] = dc * uc[2];
#pragma unroll
        for (int k = 0; k < 18; k++) yr[3 + k] = dc * mc[k];
    } else {
#pragma unroll
        for (int k = 0; k < 21; k++) yr[k] = 0.f;
    }
    float* yo = y + (size_t)c * YSTRIDE;
#pragma unroll
    for (int q = 0; q < 5; q++)
        ((float4*)yo)[q] = make_float4(yr[4 * q], yr[4 * q + 1],
                                       yr[4 * q + 2], yr[4 * q + 3]);
    yo[20] = yr[20];
}

// ---------------------------------------------------------------------------
// K_b: exclusive scan of H (196*256 = 50176 ints) in one block (49*1024).
// ---------------------------------------------------------------------------
__global__ __launch_bounds__(1024) void bscan_kernel(int* __restrict__ H) {
    const int PER = 49;
    const int t = threadIdx.x;
    const int base = t * PER;
    int v[PER];
    int sum = 0;
#pragma unroll
    for (int i = 0; i < PER; i++) {
        v[i] = H[base + i];
        sum += v[i];
    }
    __shared__ int s[1024];
    s[t] = sum;
    __syncthreads();
    for (int off = 1; off < 1024; off <<= 1) {
        int x = (t >= off) ? s[t - off] : 0;
        __syncthreads();
        s[t] += x;
        __syncthreads();
    }
    int run = s[t] - sum;
#pragma unroll
    for (int i = 0; i < PER; i++) {
        H[base + i] = run;
        run += v[i];
    }
}

// ---------------------------------------------------------------------------
// K_c: vectorized deterministic scatter into per-(bucket,block) runs.
// Payload: x = (col&511) | (row<<9), y = RAW ew bits (no dinv here).
// ---------------------------------------------------------------------------
__global__ __launch_bounds__(PTHR) void bscatter_kernel(const int* __restrict__ ei,
                                                        const float* __restrict__ ew,
                                                        const int* __restrict__ H,
                                                        int2* __restrict__ mid) {
    __shared__ int rbase[NBUCK];
    __shared__ int rcnt[NBUCK];
    for (int i = threadIdx.x; i < NBUCK; i += PTHR) {
        rbase[i] = H[i * PBLK + blockIdx.x];
        rcnt[i] = 0;
    }
    __syncthreads();
    const int tid = blockIdx.x * PTHR + threadIdx.x;
    const int4* row4 = (const int4*)ei;
    const int4* col4 = (const int4*)(ei + NE);
    const float4* ew4 = (const float4*)ew;
    for (int i = tid; i < NE / 4; i += PBLK * PTHR) {
        const int4 r = row4[i];
        const int4 c = col4[i];
        const float4 w = ew4[i];
        int b, pos;
        b = c.x >> BSH; pos = rbase[b] + atomicAdd(&rcnt[b], 1);
        mid[pos] = make_int2((c.x & (BCOLS - 1)) | (r.x << BSH), __float_as_int(w.x));
        b = c.y >> BSH; pos = rbase[b] + atomicAdd(&rcnt[b], 1);
        mid[pos] = make_int2((c.y & (BCOLS - 1)) | (r.y << BSH), __float_as_int(w.y));
        b = c.z >> BSH; pos = rbase[b] + atomicAdd(&rcnt[b], 1);
        mid[pos] = make_int2((c.z & (BCOLS - 1)) | (r.z << BSH), __float_as_int(w.z));
        b = c.w >> BSH; pos = rbase[b] + atomicAdd(&rcnt[b], 1);
        mid[pos] = make_int2((c.w & (BCOLS - 1)) | (r.w << BSH), __float_as_int(w.w));
    }
}

// ---------------------------------------------------------------------------
// K_e: bucket agg + MLP. One block (1024 thr) per 512-col bucket.
// Counting-sort the payload PHYSICALLY INTO LDS (epay, aliased with sbuf),
// then 2 independent threads per col walk the LDS run with 2-edge-batched
// float4 y gathers (y is dinv-prescaled). Partials combined via LDS; MLP
// with wave-uniform scalar Mt loads, 2-way k-split.
// ---------------------------------------------------------------------------
__global__ __launch_bounds__(AGB) void bagg_mlp_kernel(const int2* __restrict__ mid,
                                                       const int* __restrict__ H,
                                                       const float* __restrict__ dinv,
                                                       const float* __restrict__ y,
                                                       const float* __restrict__ Mt,
                                                       const float* __restrict__ b2,
                                                       float* __restrict__ out) {
    __shared__ int2 buf[CAP_E];              // 48 KB: epay, later aliased as sbuf
    __shared__ int cbase[BCOLS + 1];
    __shared__ int ccur[BCOLS];
    __shared__ float obuf[BCOLS];
    int2* epay = buf;
    float* sbuf = (float*)buf;               // 512*21 floats = 43008 B

    const int b = blockIdx.x;
    const int t = threadIdx.x;
    const int start = H[b * PBLK];
    const int end = (b + 1 < NBUCK) ? H[(b + 1) * PBLK] : NE;
    const int seg = end - start;
    const int segc = seg < CAP_E ? seg : CAP_E;

    // phase 1: per-col counts (first segc edges)
    if (t < BCOLS) ccur[t] = 0;
    __syncthreads();
    for (int i = t; i < segc; i += AGB)
        atomicAdd(&ccur[mid[start + i].x & (BCOLS - 1)], 1);
    __syncthreads();

    // phase 2: exclusive scan of 512 counts
    int myc = 0;
    if (t < BCOLS) { myc = ccur[t]; cbase[t] = myc; }
    __syncthreads();
    for (int off = 1; off < BCOLS; off <<= 1) {
        int x = 0;
        if (t < BCOLS && t >= off) x = cbase[t - off];
        __syncthreads();
        if (t < BCOLS) cbase[t] += x;
        __syncthreads();
    }
    if (t < BCOLS) {
        const int incl = cbase[t];
        cbase[t] = incl - myc;
        ccur[t] = incl - myc;
        if (t == BCOLS - 1) cbase[BCOLS] = incl;
    }
    __syncthreads();

    // phase 3: physical counting-sort into LDS: epay[pos] = (row, w)
    for (int i = t; i < segc; i += AGB) {
        const int2 p = mid[start + i];
        const int pos = atomicAdd(&ccur[p.x & (BCOLS - 1)], 1);
        epay[pos] = make_int2((int)(((unsigned)p.x) >> BSH), p.y);
    }
    __syncthreads();

    // phase 4: 2 threads per col walk the LDS run; 2-edge batches
    const int col = t & (BCOLS - 1);
    const int h = t >> 9;                    // wave-uniform
    float s21[21];
#pragma unroll
    for (int m = 0; m < 21; m++) s21[m] = 0.f;
    {
        const int s1 = cbase[col + 1];
        int i = cbase[col] + h;
        while (i < s1) {
            const bool h2 = (i + 2 < s1);
            const int2 e0 = epay[i];
            const int2 e1 = epay[h2 ? i + 2 : i];
            const float w0 = __int_as_float(e0.y);
            const float w1 = h2 ? __int_as_float(e1.y) : 0.f;
            const float4* ya = (const float4*)(y + ((size_t)e0.x << 5));
            const float4* yb = (const float4*)(y + ((size_t)e1.x << 5));
            const float4 a0 = ya[0], a1 = ya[1], a2 = ya[2], a3 = ya[3], a4 = ya[4];
            const float a20 = ((const float*)ya)[20];
            const float4 c0 = yb[0], c1 = yb[1], c2 = yb[2], c3 = yb[3], c4 = yb[4];
            const float c20 = ((const float*)yb)[20];
            s21[0]  = fmaf(w0, a0.x, s21[0]);  s21[1]  = fmaf(w0, a0.y, s21[1]);
            s21[2]  = fmaf(w0, a0.z, s21[2]);  s21[3]  = fmaf(w0, a0.w, s21[3]);
            s21[4]  = fmaf(w0, a1.x, s21[4]);  s21[5]  = fmaf(w0, a1.y, s21[5]);
            s21[6]  = fmaf(w0, a1.z, s21[6]);  s21[7]  = fmaf(w0, a1.w, s21[7]);
            s21[8]  = fmaf(w0, a2.x, s21[8]);  s21[9]  = fmaf(w0, a2.y, s21[9]);
            s21[10] = fmaf(w0, a2.z, s21[10]); s21[11] = fmaf(w0, a2.w, s21[11]);
            s21[12] = fmaf(w0, a3.x, s21[12]); s21[13] = fmaf(w0, a3.y, s21[13]);
            s21[14] = fmaf(w0, a3.z, s21[14]); s21[15] = fmaf(w0, a3.w, s21[15]);
            s21[16] = fmaf(w0, a4.x, s21[16]); s21[17] = fmaf(w0, a4.y, s21[17]);
            s21[18] = fmaf(w0, a4.z, s21[18]); s21[19] = fmaf(w0, a4.w, s21[19]);
            s21[20] = fmaf(w0, a20,  s21[20]);
            s21[0]  = fmaf(w1, c0.x, s21[0]);  s21[1]  = fmaf(w1, c0.y, s21[1]);
            s21[2]  = fmaf(w1, c0.z, s21[2]);  s21[3]  = fmaf(w1, c0.w, s21[3]);
            s21[4]  = fmaf(w1, c1.x, s21[4]);  s21[5]  = fmaf(w1, c1.y, s21[5]);
            s21[6]  = fmaf(w1, c1.z, s21[6]);  s21[7]  = fmaf(w1, c1.w, s21[7]);
            s21[8]  = fmaf(w1, c2.x, s21[8]);  s21[9]  = fmaf(w1, c2.y, s21[9]);
            s21[10] = fmaf(w1, c2.z, s21[10]); s21[11] = fmaf(w1, c2.w, s21[11]);
            s21[12] = fmaf(w1, c3.x, s21[12]); s21[13] = fmaf(w1, c3.y, s21[13]);
            s21[14] = fmaf(w1, c3.z, s21[14]); s21[15] = fmaf(w1, c3.w, s21[15]);
            s21[16] = fmaf(w1, c4.x, s21[16]); s21[17] = fmaf(w1, c4.y, s21[17]);
            s21[18] = fmaf(w1, c4.z, s21[18]); s21[19] = fmaf(w1, c4.w, s21[19]);
            s21[20] = fmaf(w1, c20,  s21[20]);
            i += 4;
        }
    }
    // overflow leftover (seg > CAP_E; statistically never): h==0 claims col
    if (seg > CAP_E && h == 0) {
        for (int i = CAP_E; i < seg; i++) {
            const int2 p = mid[start + i];
            if ((p.x & (BCOLS - 1)) == col) {
                const float w = __int_as_float(p.y);
                const float* yr = y + ((size_t)(((unsigned)p.x) >> BSH) << 5);
#pragma unroll
                for (int m = 0; m < 21; m++) s21[m] = fmaf(w, yr[m], s21[m]);
            }
        }
    }
    __syncthreads();   // all walks done before epay is reused as sbuf

    // phase 5: combine halves + self-loop + dc scale (y is prescaled: self = dc*y_c)
    const int c = b * BCOLS + col;
    if (h == 1) {
#pragma unroll
        for (int m = 0; m < 21; m++) sbuf[col * 21 + m] = s21[m];
    }
    __syncthreads();
    if (h == 0) {
        const float dc = dinv[c];
        const float* yc = y + ((size_t)c << 5);
#pragma unroll
        for (int m = 0; m < 21; m++)
            s21[m] = dc * (s21[m] + sbuf[col * 21 + m] + yc[m]);
#pragma unroll
        for (int m = 0; m < 21; m++) sbuf[col * 21 + m] = s21[m];
    }
    __syncthreads();

    // phase 6: MLP. k-half = h (wave-uniform -> scalar Mt loads).
    float sv[21];
#pragma unroll
    for (int m = 0; m < 21; m++) sv[m] = sbuf[col * 21 + m];
    float o = 0.f;
    const float* mb = Mt + h * 64 * 24;
#pragma unroll 4
    for (int k = 0; k < 64; k++) {
        const float* r = mb + k * 24;
        float hh = r[21];
#pragma unroll
        for (int m = 0; m < 21; m++) hh = fmaf(sv[m], r[m], hh);
        o = fmaf(fmaxf(hh, 0.f), r[22], o);
    }
    if (h == 1) obuf[col] = o;
    __syncthreads();
    if (h == 0 && c < NN) out[c] = o + obuf[col] + b2[0];
}

// ===========================================================================
extern "C" void kernel_launch(void* const* d_in, const int* in_sizes, int n_in,
                              void* d_out, int out_size, void* d_ws, size_t ws_size,
                              hipStream_t stream) {
    const float* ux = (const float*)d_in[0];   // user_x  [N,3]
    const float* mx = (const float*)d_in[1];   // movie_x [N,18]
    const int* ei = (const int*)d_in[2];       // edge_index [2,E]
    const float* ew = (const float*)d_in[3];   // edge_attr [E]
    const float* Wu = (const float*)d_in[4];   // [3,64]
    const float* bu = (const float*)d_in[5];   // [64]
    const float* Wm = (const float*)d_in[6];   // [18,64]
    const float* bm = (const float*)d_in[7];   // [64]
    const float* W1 = (const float*)d_in[8];   // [128,128]
    const float* b1 = (const float*)d_in[9];   // [128]
    const float* W2 = (const float*)d_in[10];  // [128,1]
    const float* b2 = (const float*)d_in[11];  // [1]
    float* out = (float*)d_out;

    char* ws = (char*)d_ws;
    float* dinv = (float*)ws;                    // NNP*4 = 401,408 B (deg->dinv)
    int*   H    = (int*)(ws + 401408);           // 50176*4 = 200,704 B
    float* Mt   = (float*)(ws + 602112);         // 12,288 B
    float* y    = (float*)(ws + 614400);         // NNP*128 = 12,845,056 B (128-B aligned)
    int2*  mid  = (int2*)(ws + 13459456);        // NE*8 = 8 MB
    // total ~21.5 MB

    hipMemsetAsync(dinv, 0, NNP * sizeof(float), stream);
    fuse_kernel<<<1, 128, 0, stream>>>(Wu, bu, Wm, bm, W1, b1, W2, Mt);
    histdeg_kernel<<<PBLK, PTHR, 0, stream>>>(ei + NE, ew, H, dinv);
    dinv_kernel<<<(NNP + 255) / 256, 256, 0, stream>>>(dinv);
    ypack_kernel<<<(NNP + 255) / 256, 256, 0, stream>>>(ux, mx, dinv, y);
    bscan_kernel<<<1, 1024, 0, stream>>>(H);
    bscatter_kernel<<<PBLK, PTHR, 0, stream>>>(ei, ew, H, mid);
    bagg_mlp_kernel<<<NBUCK, AGB, 0, stream>>>(mid, H, dinv, y, Mt, b2, out);
}